// Round 8
// baseline (178.948 us; speedup 1.0000x reference)
//
#include <hip/hip_runtime.h>
#include <math.h>

#define BDIM 256
constexpr float GAMMA = 0.2f;
constexpr int Bn = 1024;
constexpr int Cn = 100000;
constexpr int Tn = 20;
constexpr int HALF = Cn / 2;            // 50000 floats per half-row
constexpr int N4H = HALF / 4;           // 12500 float4s per half-row
constexpr int NBLK = 2 * Bn;            // 2048 half-row blocks
constexpr float THR = 30.0f;            // defer-max: m_final >= true_max - THR

// process one float4 into an independent (m, s) stream
#define PROC(v, mm, ss)                                                      \
  do {                                                                       \
    const float vm_ = fmaxf(fmaxf((v).x, (v).y), fmaxf((v).z, (v).w));       \
    if (vm_ > (mm) + THR) {             /* rare after warm-up */             \
      (ss) *= __expf((mm) - vm_);       /* first iter: exp(-inf)=0 */        \
      (mm) = vm_;                                                            \
    }                                                                        \
    (ss) += (__expf((v).x - (mm)) + __expf((v).y - (mm)))                    \
          + (__expf((v).z - (mm)) + __expf((v).w - (mm)));                   \
  } while (0)

// ws layout (floats):
//   [0, 2048)        m per half-block
//   [2048, 4096)     s per half-block
//   [4096, 5120)     x_tgt per row
//   [5120, 6144)     mg    per row   (max over exclusion-set gathered values)
//   [6144, 7168)     E_g   per row   (sum exp(xv - mg) over exclusion set)
//   [7168, 8192)     x_rel per row   (min over valid rest)
//   [8192, 9216)     cnt   per row   (# valid rest)
//   [9216]           completion counter (int, memset to 0 each call)

// Single fused kernel: streaming LSE per half-row; half==0 blocks also emit
// merge-safe tail partials; the LAST block to finish does the final reduce.
__global__ __launch_bounds__(BDIM) void rll_fused_kernel(
    const float* __restrict__ x, const int* __restrict__ y,
    float* __restrict__ ws, float* __restrict__ out) {
  const int bid = blockIdx.x;
  const int row = bid >> 1, half = bid & 1;
  const int tid = threadIdx.x;
  const float4* __restrict__ x4 =
      reinterpret_cast<const float4*>(x + (size_t)row * Cn + half * HALF);

  // --- early-issued T-gather (half==0, wave 0, lanes 0..19) ---
  int gvi = -1; float gxv = 0.0f;
  if (half == 0 && tid < Tn) {
    gvi = y[(size_t)row * Tn + tid];
    gxv = x[(size_t)row * Cn + (gvi >= 0 ? gvi : 0)];  // t=0 (target) always valid
  }

  // --- 4 independent (m, s) streams; compiler-scheduled ---
  float m0 = -INFINITY, m1 = -INFINITY, m2 = -INFINITY, m3 = -INFINITY;
  float s0 = 0.f, s1 = 0.f, s2 = 0.f, s3 = 0.f;

  int i = tid;
  for (; i + 3 * BDIM < N4H; i += 4 * BDIM) {
    const float4 a = x4[i];
    const float4 b = x4[i + BDIM];
    const float4 c = x4[i + 2 * BDIM];
    const float4 d = x4[i + 3 * BDIM];
    PROC(a, m0, s0);
    PROC(b, m1, s1);
    PROC(c, m2, s2);
    PROC(d, m3, s3);
  }
  for (; i < N4H; i += BDIM) {
    const float4 t = x4[i];
    PROC(t, m0, s0);
  }

  // merge 4 streams
  float m = fmaxf(fmaxf(m0, m1), fmaxf(m2, m3));
  float s = (s0 * __expf(m0 - m) + s1 * __expf(m1 - m))
          + (s2 * __expf(m2 - m) + s3 * __expf(m3 - m));

  // wave (64-lane) butterfly reduce
  #pragma unroll
  for (int off = 1; off < 64; off <<= 1) {
    const float mo = __shfl_xor(m, off);
    const float so = __shfl_xor(s, off);
    const float mn = fmaxf(m, mo);
    s = s * __expf(m - mn) + so * __expf(mo - mn);
    m = mn;
  }

  // cross-wave combine (4 waves)
  __shared__ float sm[BDIM / 64], ss[BDIM / 64];
  const int wave = tid >> 6, lane = tid & 63;
  if (lane == 0) { sm[wave] = m; ss[wave] = s; }
  __syncthreads();
  if (tid == 0) {
    m = sm[0]; s = ss[0];
    #pragma unroll
    for (int w = 1; w < BDIM / 64; ++w) {
      const float mo = sm[w], so = ss[w];
      const float mn = fmaxf(m, mo);
      s = s * __expf(m - mn) + so * __expf(mo - mn);
      m = mn;
    }
    ws[bid]        = m;
    ws[2048 + bid] = s;
  }

  // --- tail partials (half==0, wave 0 only; all stores land on tid 0) ---
  if (half == 0 && wave == 0) {
    const int t = tid;  // 0..63
    bool dup = false;
    #pragma unroll
    for (int u = 0; u < Tn - 1; ++u) {
      const int vu = __shfl(gvi, u);
      dup = dup || ((u < t) && (vu == gvi));
    }
    const bool validrest = (t >= 1) && (t < Tn) && (gvi >= 0);
    const bool inexcl = (t == 0) || (validrest && !dup);

    float mg   = inexcl ? gxv : -INFINITY;       // max over exclusion set
    float xrel = validrest ? gxv : INFINITY;     // min over valid rest
    float cnt  = validrest ? 1.0f : 0.0f;
    #pragma unroll
    for (int off = 1; off < 64; off <<= 1) {
      mg   = fmaxf(mg, __shfl_xor(mg, off));
      xrel = fminf(xrel, __shfl_xor(xrel, off));
      cnt += __shfl_xor(cnt, off);
    }
    float eg = inexcl ? __expf(gxv - mg) : 0.0f;
    #pragma unroll
    for (int off = 1; off < 64; off <<= 1) eg += __shfl_xor(eg, off);

    if (t == 0) {
      ws[4096 + row] = gxv;   // x_tgt (lane 0 holds target)
      ws[5120 + row] = mg;
      ws[6144 + row] = eg;
      ws[7168 + row] = xrel;
      ws[8192 + row] = cnt;
    }
  }

  // --- last-block-done final reduce (saves the second kernel launch) ---
  __shared__ int amLast;
  __syncthreads();                       // all ws stores (by tid 0) complete
  if (tid == 0) {
    int* counter = reinterpret_cast<int*>(ws + 9216);
    const int old = __hip_atomic_fetch_add(counter, 1, __ATOMIC_ACQ_REL,
                                           __HIP_MEMORY_SCOPE_AGENT);
    amLast = (old == NBLK - 1);          // acquire: later reads see all releases
  }
  __syncthreads();

  if (amLast) {
    float v1 = 0.f, v2 = 0.f, v3 = 0.f;
    for (int r = tid; r < Bn; r += BDIM) {      // 4 rows per thread, fixed order
      const float ma = ws[2 * r],        mb2 = ws[2 * r + 1];
      const float sa = ws[2048 + 2 * r], sb2 = ws[2048 + 2 * r + 1];
      const float mm = fmaxf(ma, mb2);
      const float sum = sa * __expf(ma - mm) + sb2 * __expf(mb2 - mm);
      const float logZ = mm + logf(sum);

      const float x_tgt = ws[4096 + r];
      const float mg    = ws[5120 + r];
      const float eg    = ws[6144 + r];
      const float xrel  = ws[7168 + r];
      const float cnt   = ws[8192 + r];

      v1 += logZ - x_tgt;                       // loss1

      if (cnt >= 1.0f) {
        v3 += 1.0f;                             // active
        const float exsum = eg * __expf(mg - mm);   // mg - mm <= THR
        float s_cand = sum - exsum;
        if (s_cand < 1e-30f) s_cand = 1e-30f;
        const float lse_cand = mm + logf(s_cand);
        const float d = lse_cand - xrel;
        v2 += (d >= 0.0f) ? (d + log1pf(__expf(-d))) : log1pf(__expf(d));
      }
    }

    #pragma unroll
    for (int off = 1; off < 64; off <<= 1) {
      v1 += __shfl_xor(v1, off);
      v2 += __shfl_xor(v2, off);
      v3 += __shfl_xor(v3, off);
    }
    __shared__ float a1[BDIM / 64], a2[BDIM / 64], a3[BDIM / 64];
    if (lane == 0) { a1[wave] = v1; a2[wave] = v2; a3[wave] = v3; }
    __syncthreads();
    if (tid == 0) {
      float t1 = 0.f, t2 = 0.f, t3 = 0.f;
      #pragma unroll
      for (int w = 0; w < BDIM / 64; ++w) { t1 += a1[w]; t2 += a2[w]; t3 += a3[w]; }
      out[0] = t1 / (float)Bn + GAMMA * (t2 / (1e-8f + t3));
    }
  }
}

extern "C" void kernel_launch(void* const* d_in, const int* in_sizes, int n_in,
                              void* d_out, int out_size, void* d_ws, size_t ws_size,
                              hipStream_t stream) {
  const float* x = (const float*)d_in[0];
  const int*   y = (const int*)d_in[1];
  float* out = (float*)d_out;
  float* ws  = (float*)d_ws;

  // zero the completion counter (4 bytes at float index 9216) each call
  hipMemsetAsync(ws + 9216, 0, sizeof(int), stream);
  rll_fused_kernel<<<NBLK, BDIM, 0, stream>>>(x, y, ws, out);
}

// Round 9
// 79.452 us; speedup vs baseline: 2.2523x; 2.2523x over previous
//
#include <hip/hip_runtime.h>
#include <math.h>

#define BDIM 256
constexpr float GAMMA = 0.2f;
constexpr int Bn = 1024;
constexpr int Cn = 100000;
constexpr int Tn = 20;
constexpr int HALF = Cn / 2;            // 50000 floats per half-row
constexpr int N4H = HALF / 4;           // 12500 float4s per half-row
constexpr float THR = 30.0f;            // defer-max: m_final >= true_max - THR

// process one float4 into an independent (m, s) stream
#define PROC(v, mm, ss)                                                      \
  do {                                                                       \
    const float vm_ = fmaxf(fmaxf((v).x, (v).y), fmaxf((v).z, (v).w));       \
    if (vm_ > (mm) + THR) {             /* rare after warm-up */             \
      (ss) *= __expf((mm) - vm_);       /* first iter: exp(-inf)=0 */        \
      (mm) = vm_;                                                            \
    }                                                                        \
    (ss) += (__expf((v).x - (mm)) + __expf((v).y - (mm)))                    \
          + (__expf((v).z - (mm)) + __expf((v).w - (mm)));                   \
  } while (0)

// ws layout (floats):
//   [0, 2048)        m per half-block
//   [2048, 4096)     s per half-block
//   [4096, 5120)     x_tgt per row
//   [5120, 6144)     mg    per row   (max over exclusion-set gathered values)
//   [6144, 7168)     E_g   per row   (sum exp(xv - mg) over exclusion set)
//   [7168, 8192)     x_rel per row   (min over valid rest)
//   [8192, 9216)     cnt   per row   (# valid rest)

// Kernel 1: streaming LSE over one half-row per block (grid 2048).
// launch_bounds(256,6): cap VGPR ~85 -> 6 waves/SIMD occupancy (was ~4 at
// natural VGPR ~80+). half==0 blocks also gather the T=20 scattered values
// (issued at entry, latency hidden under the stream) and emit merge-safe
// tail partials.
__global__ __launch_bounds__(BDIM, 6) void rll_half_kernel(
    const float* __restrict__ x, const int* __restrict__ y,
    float* __restrict__ ws) {
  const int bid = blockIdx.x;
  const int row = bid >> 1, half = bid & 1;
  const int tid = threadIdx.x;
  const float4* __restrict__ x4 =
      reinterpret_cast<const float4*>(x + (size_t)row * Cn + half * HALF);

  // --- early-issued T-gather (half==0, wave 0, lanes 0..19) ---
  int gvi = -1; float gxv = 0.0f;
  if (half == 0 && tid < Tn) {
    gvi = y[(size_t)row * Tn + tid];
    gxv = x[(size_t)row * Cn + (gvi >= 0 ? gvi : 0)];  // t=0 (target) always valid
  }

  // --- 4 independent (m, s) streams; compiler-scheduled ---
  float m0 = -INFINITY, m1 = -INFINITY, m2 = -INFINITY, m3 = -INFINITY;
  float s0 = 0.f, s1 = 0.f, s2 = 0.f, s3 = 0.f;

  int i = tid;
  for (; i + 3 * BDIM < N4H; i += 4 * BDIM) {
    const float4 a = x4[i];
    const float4 b = x4[i + BDIM];
    const float4 c = x4[i + 2 * BDIM];
    const float4 d = x4[i + 3 * BDIM];
    PROC(a, m0, s0);
    PROC(b, m1, s1);
    PROC(c, m2, s2);
    PROC(d, m3, s3);
  }
  for (; i < N4H; i += BDIM) {
    const float4 t = x4[i];
    PROC(t, m0, s0);
  }

  // merge 4 streams
  float m = fmaxf(fmaxf(m0, m1), fmaxf(m2, m3));
  float s = (s0 * __expf(m0 - m) + s1 * __expf(m1 - m))
          + (s2 * __expf(m2 - m) + s3 * __expf(m3 - m));

  // wave (64-lane) butterfly reduce
  #pragma unroll
  for (int off = 1; off < 64; off <<= 1) {
    const float mo = __shfl_xor(m, off);
    const float so = __shfl_xor(s, off);
    const float mn = fmaxf(m, mo);
    s = s * __expf(m - mn) + so * __expf(mo - mn);
    m = mn;
  }

  // cross-wave combine (4 waves)
  __shared__ float sm[BDIM / 64], ss[BDIM / 64];
  const int wave = tid >> 6, lane = tid & 63;
  if (lane == 0) { sm[wave] = m; ss[wave] = s; }
  __syncthreads();
  if (tid == 0) {
    m = sm[0]; s = ss[0];
    #pragma unroll
    for (int w = 1; w < BDIM / 64; ++w) {
      const float mo = sm[w], so = ss[w];
      const float mn = fmaxf(m, mo);
      s = s * __expf(m - mn) + so * __expf(mo - mn);
      m = mn;
    }
    ws[bid]        = m;
    ws[2048 + bid] = s;
  }

  // --- tail partials (half==0, wave 0 only; all stores land on tid 0) ---
  if (half == 0 && wave == 0) {
    const int t = tid;  // 0..63
    // dup_t = exists u<t with vi_u == vi_t (only matters when gvi>=0)
    bool dup = false;
    #pragma unroll
    for (int u = 0; u < Tn - 1; ++u) {
      const int vu = __shfl(gvi, u);
      dup = dup || ((u < t) && (vu == gvi));
    }
    const bool validrest = (t >= 1) && (t < Tn) && (gvi >= 0);
    const bool inexcl = (t == 0) || (validrest && !dup);

    float mg   = inexcl ? gxv : -INFINITY;       // max over exclusion set
    float xrel = validrest ? gxv : INFINITY;     // min over valid rest
    float cnt  = validrest ? 1.0f : 0.0f;
    #pragma unroll
    for (int off = 1; off < 64; off <<= 1) {
      mg   = fmaxf(mg, __shfl_xor(mg, off));
      xrel = fminf(xrel, __shfl_xor(xrel, off));
      cnt += __shfl_xor(cnt, off);
    }
    // E_g = sum over exclusion set of exp(xv - mg)   (mg uniform now)
    float eg = inexcl ? __expf(gxv - mg) : 0.0f;
    #pragma unroll
    for (int off = 1; off < 64; off <<= 1) eg += __shfl_xor(eg, off);

    if (t == 0) {
      ws[4096 + row] = gxv;   // x_tgt (lane 0 holds target)
      ws[5120 + row] = mg;
      ws[6144 + row] = eg;
      ws[7168 + row] = xrel;
      ws[8192 + row] = cnt;
    }
  }
}

// Kernel 2: one block, 1024 threads, one row per thread.
// Merge half partials, reconstruct loss terms, block-reduce to scalar.
__global__ __launch_bounds__(1024) void rll_final_kernel(
    const float* __restrict__ ws, float* __restrict__ out) {
  const int r = threadIdx.x;

  const float ma = ws[2 * r],        mb = ws[2 * r + 1];
  const float sa = ws[2048 + 2 * r], sb = ws[2048 + 2 * r + 1];
  const float m = fmaxf(ma, mb);
  const float s = sa * __expf(ma - m) + sb * __expf(mb - m);
  const float logZ = m + logf(s);

  const float x_tgt = ws[4096 + r];
  const float mg    = ws[5120 + r];
  const float eg    = ws[6144 + r];
  const float xrel  = ws[7168 + r];
  const float cnt   = ws[8192 + r];

  const float loss1 = logZ - x_tgt;

  float loss2 = 0.0f, act = 0.0f;
  if (cnt >= 1.0f) {
    act = 1.0f;
    const float exsum = eg * __expf(mg - m);    // mg - m <= THR -> no overflow
    float s_cand = s - exsum;                   // remove excluded terms
    if (s_cand < 1e-30f) s_cand = 1e-30f;       // guard
    const float lse_cand = m + logf(s_cand);
    const float d = lse_cand - xrel;
    // rel_loss = logaddexp(lse_cand, x_rel) - x_rel
    loss2 = (d >= 0.0f) ? (d + log1pf(__expf(-d))) : log1pf(__expf(d));
  }

  // block reduce {loss1, loss2, act} over 1024 threads (16 waves)
  float v1 = loss1, v2 = loss2, v3 = act;
  #pragma unroll
  for (int off = 1; off < 64; off <<= 1) {
    v1 += __shfl_xor(v1, off);
    v2 += __shfl_xor(v2, off);
    v3 += __shfl_xor(v3, off);
  }
  __shared__ float a1[16], a2[16], a3[16];
  const int wave = r >> 6, lane = r & 63;
  if (lane == 0) { a1[wave] = v1; a2[wave] = v2; a3[wave] = v3; }
  __syncthreads();
  if (r == 0) {
    float t1 = 0.f, t2 = 0.f, t3 = 0.f;
    #pragma unroll
    for (int w = 0; w < 16; ++w) { t1 += a1[w]; t2 += a2[w]; t3 += a3[w]; }
    out[0] = t1 / (float)Bn + GAMMA * (t2 / (1e-8f + t3));
  }
}

extern "C" void kernel_launch(void* const* d_in, const int* in_sizes, int n_in,
                              void* d_out, int out_size, void* d_ws, size_t ws_size,
                              hipStream_t stream) {
  const float* x = (const float*)d_in[0];
  const int*   y = (const int*)d_in[1];
  float* out = (float*)d_out;
  float* ws  = (float*)d_ws;

  rll_half_kernel<<<2 * Bn, BDIM, 0, stream>>>(x, y, ws);
  rll_final_kernel<<<1, 1024, 0, stream>>>(ws, out);
}

// Round 11
// 70.467 us; speedup vs baseline: 2.5395x; 1.1275x over previous
//
#include <hip/hip_runtime.h>
#include <math.h>

#define BDIM 256
constexpr float GAMMA = 0.2f;
constexpr int Bn = 1024;
constexpr int Cn = 100000;
constexpr int Tn = 20;
constexpr int HALF = Cn / 2;            // 50000 floats per half-row
constexpr int N4H = HALF / 4;           // 12500 float4s per half-row
constexpr float THR = 30.0f;            // defer-max: m_final >= true_max - THR

// native vector type: accepted by __builtin_nontemporal_load (HIP float4 is a struct, rejected)
typedef float fvec4 __attribute__((ext_vector_type(4)));

// process one fvec4 into an independent (m, s) stream
#define PROC(v, mm, ss)                                                      \
  do {                                                                       \
    const float vm_ = fmaxf(fmaxf((v)[0], (v)[1]), fmaxf((v)[2], (v)[3]));   \
    if (vm_ > (mm) + THR) {             /* rare after warm-up */             \
      (ss) *= __expf((mm) - vm_);       /* first iter: exp(-inf)=0 */        \
      (mm) = vm_;                                                            \
    }                                                                        \
    (ss) += (__expf((v)[0] - (mm)) + __expf((v)[1] - (mm)))                  \
          + (__expf((v)[2] - (mm)) + __expf((v)[3] - (mm)));                 \
  } while (0)

// ws layout (floats):
//   [0, 2048)        m per half-block
//   [2048, 4096)     s per half-block
//   [4096, 5120)     x_tgt per row
//   [5120, 6144)     mg    per row   (max over exclusion-set gathered values)
//   [6144, 7168)     E_g   per row   (sum exp(xv - mg) over exclusion set)
//   [7168, 8192)     x_rel per row   (min over valid rest)
//   [8192, 9216)     cnt   per row   (# valid rest)

// Kernel 1: streaming LSE over one half-row per block (grid 2048).
// Streaming reads are NON-TEMPORAL (read-once data; bypass L2 allocation).
// half==0 blocks also gather the T=20 scattered values (issued at entry,
// latency hidden under the stream) and emit merge-safe tail partials.
__global__ __launch_bounds__(BDIM) void rll_half_kernel(
    const float* __restrict__ x, const int* __restrict__ y,
    float* __restrict__ ws) {
  const int bid = blockIdx.x;
  const int row = bid >> 1, half = bid & 1;
  const int tid = threadIdx.x;
  const fvec4* __restrict__ x4 =
      reinterpret_cast<const fvec4*>(x + (size_t)row * Cn + half * HALF);

  // --- early-issued T-gather (half==0, wave 0, lanes 0..19) ---
  int gvi = -1; float gxv = 0.0f;
  if (half == 0 && tid < Tn) {
    gvi = y[(size_t)row * Tn + tid];
    gxv = x[(size_t)row * Cn + (gvi >= 0 ? gvi : 0)];  // t=0 (target) always valid
  }

  // --- 4 independent (m, s) streams; compiler-scheduled; nt loads ---
  float m0 = -INFINITY, m1 = -INFINITY, m2 = -INFINITY, m3 = -INFINITY;
  float s0 = 0.f, s1 = 0.f, s2 = 0.f, s3 = 0.f;

  int i = tid;
  for (; i + 3 * BDIM < N4H; i += 4 * BDIM) {
    const fvec4 a = __builtin_nontemporal_load(x4 + i);
    const fvec4 b = __builtin_nontemporal_load(x4 + i + BDIM);
    const fvec4 c = __builtin_nontemporal_load(x4 + i + 2 * BDIM);
    const fvec4 d = __builtin_nontemporal_load(x4 + i + 3 * BDIM);
    PROC(a, m0, s0);
    PROC(b, m1, s1);
    PROC(c, m2, s2);
    PROC(d, m3, s3);
  }
  for (; i < N4H; i += BDIM) {
    const fvec4 t = __builtin_nontemporal_load(x4 + i);
    PROC(t, m0, s0);
  }

  // merge 4 streams
  float m = fmaxf(fmaxf(m0, m1), fmaxf(m2, m3));
  float s = (s0 * __expf(m0 - m) + s1 * __expf(m1 - m))
          + (s2 * __expf(m2 - m) + s3 * __expf(m3 - m));

  // wave (64-lane) butterfly reduce
  #pragma unroll
  for (int off = 1; off < 64; off <<= 1) {
    const float mo = __shfl_xor(m, off);
    const float so = __shfl_xor(s, off);
    const float mn = fmaxf(m, mo);
    s = s * __expf(m - mn) + so * __expf(mo - mn);
    m = mn;
  }

  // cross-wave combine (4 waves)
  __shared__ float sm[BDIM / 64], ss[BDIM / 64];
  const int wave = tid >> 6, lane = tid & 63;
  if (lane == 0) { sm[wave] = m; ss[wave] = s; }
  __syncthreads();
  if (tid == 0) {
    m = sm[0]; s = ss[0];
    #pragma unroll
    for (int w = 1; w < BDIM / 64; ++w) {
      const float mo = sm[w], so = ss[w];
      const float mn = fmaxf(m, mo);
      s = s * __expf(m - mn) + so * __expf(mo - mn);
      m = mn;
    }
    ws[bid]        = m;
    ws[2048 + bid] = s;
  }

  // --- tail partials (half==0, wave 0 only; all stores land on tid 0) ---
  if (half == 0 && wave == 0) {
    const int t = tid;  // 0..63
    // dup_t = exists u<t with vi_u == vi_t (only matters when gvi>=0)
    bool dup = false;
    #pragma unroll
    for (int u = 0; u < Tn - 1; ++u) {
      const int vu = __shfl(gvi, u);
      dup = dup || ((u < t) && (vu == gvi));
    }
    const bool validrest = (t >= 1) && (t < Tn) && (gvi >= 0);
    const bool inexcl = (t == 0) || (validrest && !dup);

    float mg   = inexcl ? gxv : -INFINITY;       // max over exclusion set
    float xrel = validrest ? gxv : INFINITY;     // min over valid rest
    float cnt  = validrest ? 1.0f : 0.0f;
    #pragma unroll
    for (int off = 1; off < 64; off <<= 1) {
      mg   = fmaxf(mg, __shfl_xor(mg, off));
      xrel = fminf(xrel, __shfl_xor(xrel, off));
      cnt += __shfl_xor(cnt, off);
    }
    // E_g = sum over exclusion set of exp(xv - mg)   (mg uniform now)
    float eg = inexcl ? __expf(gxv - mg) : 0.0f;
    #pragma unroll
    for (int off = 1; off < 64; off <<= 1) eg += __shfl_xor(eg, off);

    if (t == 0) {
      ws[4096 + row] = gxv;   // x_tgt (lane 0 holds target)
      ws[5120 + row] = mg;
      ws[6144 + row] = eg;
      ws[7168 + row] = xrel;
      ws[8192 + row] = cnt;
    }
  }
}

// Kernel 2: one block, 1024 threads, one row per thread.
// Merge half partials, reconstruct loss terms, block-reduce to scalar.
__global__ __launch_bounds__(1024) void rll_final_kernel(
    const float* __restrict__ ws, float* __restrict__ out) {
  const int r = threadIdx.x;

  const float ma = ws[2 * r],        mb = ws[2 * r + 1];
  const float sa = ws[2048 + 2 * r], sb = ws[2048 + 2 * r + 1];
  const float m = fmaxf(ma, mb);
  const float s = sa * __expf(ma - m) + sb * __expf(mb - m);
  const float logZ = m + logf(s);

  const float x_tgt = ws[4096 + r];
  const float mg    = ws[5120 + r];
  const float eg    = ws[6144 + r];
  const float xrel  = ws[7168 + r];
  const float cnt   = ws[8192 + r];

  const float loss1 = logZ - x_tgt;

  float loss2 = 0.0f, act = 0.0f;
  if (cnt >= 1.0f) {
    act = 1.0f;
    const float exsum = eg * __expf(mg - m);    // mg - m <= THR -> no overflow
    float s_cand = s - exsum;                   // remove excluded terms
    if (s_cand < 1e-30f) s_cand = 1e-30f;       // guard
    const float lse_cand = m + logf(s_cand);
    const float d = lse_cand - xrel;
    // rel_loss = logaddexp(lse_cand, x_rel) - x_rel
    loss2 = (d >= 0.0f) ? (d + log1pf(__expf(-d))) : log1pf(__expf(d));
  }

  // block reduce {loss1, loss2, act} over 1024 threads (16 waves)
  float v1 = loss1, v2 = loss2, v3 = act;
  #pragma unroll
  for (int off = 1; off < 64; off <<= 1) {
    v1 += __shfl_xor(v1, off);
    v2 += __shfl_xor(v2, off);
    v3 += __shfl_xor(v3, off);
  }
  __shared__ float a1[16], a2[16], a3[16];
  const int wave = r >> 6, lane = r & 63;
  if (lane == 0) { a1[wave] = v1; a2[wave] = v2; a3[wave] = v3; }
  __syncthreads();
  if (r == 0) {
    float t1 = 0.f, t2 = 0.f, t3 = 0.f;
    #pragma unroll
    for (int w = 0; w < 16; ++w) { t1 += a1[w]; t2 += a2[w]; t3 += a3[w]; }
    out[0] = t1 / (float)Bn + GAMMA * (t2 / (1e-8f + t3));
  }
}

extern "C" void kernel_launch(void* const* d_in, const int* in_sizes, int n_in,
                              void* d_out, int out_size, void* d_ws, size_t ws_size,
                              hipStream_t stream) {
  const float* x = (const float*)d_in[0];
  const int*   y = (const int*)d_in[1];
  float* out = (float*)d_out;
  float* ws  = (float*)d_ws;

  rll_half_kernel<<<2 * Bn, BDIM, 0, stream>>>(x, y, ws);
  rll_final_kernel<<<1, 1024, 0, stream>>>(ws, out);
}